// Round 1
// baseline (7600.546 us; speedup 1.0000x reference)
//
#include <hip/hip_runtime.h>

#define N_NODES 50000
#define N_EDGES 800000
#define N_GRAPHS 512
#define IN_C 128
#define HID 256
#define OUT_C 16

// ---------------------------------------------------------------------------
// Scatter-add: agg[dst[e]] += h[src[e]] over all edges.
// Each edge is handled by C/4 consecutive threads (float4 gather, 4 atomics).
// perShift = log2(C/4): 5 for C=128, 6 for C=256.
// ---------------------------------------------------------------------------
__global__ void scatter_add_kernel(const float* __restrict__ h,
                                   const int* __restrict__ src,
                                   const int* __restrict__ dst,
                                   float* __restrict__ agg,
                                   int E, int C, int perShift) {
    long tid = (long)blockIdx.x * blockDim.x + threadIdx.x;
    int per = 1 << perShift;
    long total = (long)E * per;
    if (tid >= total) return;
    int e = (int)(tid >> perShift);
    int j = (int)(tid & (per - 1)) << 2;
    int s = src[e];
    int d = dst[e];
    float4 v = *(const float4*)(h + (long)s * C + j);
    float* p = agg + (long)d * C + j;
    atomicAdd(p + 0, v.x);
    atomicAdd(p + 1, v.y);
    atomicAdd(p + 2, v.z);
    atomicAdd(p + 3, v.w);
}

// ---------------------------------------------------------------------------
// Tiled fp32 GEMM with fused bias + optional ReLU.
// C[M,N] = (A[M,K] @ W[K,N]) + bias, BM=BN=64, BK=32, 256 thr, 4x4 microtile.
// ---------------------------------------------------------------------------
__global__ __launch_bounds__(256) void gemm_bias_relu(
    const float* __restrict__ A,   // M x K, row-major
    const float* __restrict__ W,   // K x N, row-major
    const float* __restrict__ bias,// N
    float* __restrict__ C,         // M x N
    int M, int K, int N, int doRelu) {
    const int BM = 64, BN = 64, BK = 32;
    __shared__ float As[BK][BM];      // transposed: [k][m]
    __shared__ float Bs[BK][BN + 4];  // +4 pad (keeps float4 LDS writes aligned: 68*4B = 272B, 16B-aligned)

    int t = threadIdx.x;
    int tx = t & 15;   // col group (4 cols each)
    int ty = t >> 4;   // row group (4 rows each)
    int block_row = blockIdx.x * BM;
    int block_col = blockIdx.y * BN;

    float acc[4][4] = {};

    for (int k0 = 0; k0 < K; k0 += BK) {
        // A tile: 64 rows x 32 k. 512 float4 loads, 2 per thread.
        #pragma unroll
        for (int l = 0; l < 2; ++l) {
            int idx = t + l * 256;              // [0, 512)
            int m = idx >> 3;                   // /8
            int kk = (idx & 7) << 2;            // *4
            int grow = block_row + m;
            float4 v = make_float4(0.f, 0.f, 0.f, 0.f);
            if (grow < M) v = *(const float4*)(A + (long)grow * K + k0 + kk);
            As[kk + 0][m] = v.x;
            As[kk + 1][m] = v.y;
            As[kk + 2][m] = v.z;
            As[kk + 3][m] = v.w;
        }
        // B tile: 32 k x 64 n. 512 float4 loads, 2 per thread.
        #pragma unroll
        for (int l = 0; l < 2; ++l) {
            int idx = t + l * 256;              // [0, 512)
            int kk = idx >> 4;                  // /16
            int nn = (idx & 15) << 2;           // *4
            float4 v = *(const float4*)(W + (long)(k0 + kk) * N + block_col + nn);
            *(float4*)&Bs[kk][nn] = v;
        }
        __syncthreads();

        #pragma unroll
        for (int kk = 0; kk < BK; ++kk) {
            float a[4], b[4];
            #pragma unroll
            for (int i = 0; i < 4; ++i) a[i] = As[kk][ty * 4 + i];
            #pragma unroll
            for (int j = 0; j < 4; ++j) b[j] = Bs[kk][tx * 4 + j];
            #pragma unroll
            for (int i = 0; i < 4; ++i)
                #pragma unroll
                for (int j = 0; j < 4; ++j)
                    acc[i][j] += a[i] * b[j];
        }
        __syncthreads();
    }

    // Epilogue: bias + relu, float4 stores.
    int gcol = block_col + tx * 4;
    float4 bv = *(const float4*)(bias + gcol);
    #pragma unroll
    for (int i = 0; i < 4; ++i) {
        int grow = block_row + ty * 4 + i;
        if (grow >= M) continue;
        float4 o;
        o.x = acc[i][0] + bv.x;
        o.y = acc[i][1] + bv.y;
        o.z = acc[i][2] + bv.z;
        o.w = acc[i][3] + bv.w;
        if (doRelu) {
            o.x = fmaxf(o.x, 0.f); o.y = fmaxf(o.y, 0.f);
            o.z = fmaxf(o.z, 0.f); o.w = fmaxf(o.w, 0.f);
        }
        *(float4*)(C + (long)grow * N + gcol) = o;
    }
}

// ---------------------------------------------------------------------------
// Global mean-pool (phase 1): atomic accumulate sums[g, :] and counts[g].
// One thread per (node, 4-channel chunk).
// ---------------------------------------------------------------------------
__global__ void pool_kernel(const float* __restrict__ h,
                            const int* __restrict__ batch,
                            float* __restrict__ sums,
                            float* __restrict__ counts) {
    long tid = (long)blockIdx.x * blockDim.x + threadIdx.x;
    long total = (long)N_NODES * (HID / 4);
    if (tid >= total) return;
    int n = (int)(tid >> 6);          // HID/4 = 64 chunks per node
    int j = (int)(tid & 63) << 2;
    int g = batch[n];
    float4 v = *(const float4*)(h + (long)n * HID + j);
    float* p = sums + (long)g * HID + j;
    atomicAdd(p + 0, v.x);
    atomicAdd(p + 1, v.y);
    atomicAdd(p + 2, v.z);
    atomicAdd(p + 3, v.w);
    if (j == 0) atomicAdd(counts + g, 1.0f);
}

// ---------------------------------------------------------------------------
// Head MLP: one block per graph. pooled = sums/count; relu(pooled@w1+b1)@w2+b2.
// ---------------------------------------------------------------------------
__global__ __launch_bounds__(256) void final_mlp_kernel(
    const float* __restrict__ sums, const float* __restrict__ counts,
    const float* __restrict__ w1, const float* __restrict__ b1,
    const float* __restrict__ w2, const float* __restrict__ b2,
    float* __restrict__ out) {
    __shared__ float row[HID];
    __shared__ float hid[HID];
    int g = blockIdx.x;
    int t = threadIdx.x;
    float cnt = fmaxf(counts[g], 1.0f);
    row[t] = sums[(long)g * HID + t] / cnt;
    __syncthreads();
    float acc = b1[t];
    for (int k = 0; k < HID; ++k) acc += row[k] * w1[k * HID + t];
    hid[t] = fmaxf(acc, 0.f);
    __syncthreads();
    if (t < OUT_C) {
        float o = b2[t];
        for (int k = 0; k < HID; ++k) o += hid[k] * w2[k * OUT_C + t];
        out[(long)g * OUT_C + t] = o;
    }
}

// ---------------------------------------------------------------------------
extern "C" void kernel_launch(void* const* d_in, const int* in_sizes, int n_in,
                              void* d_out, int out_size, void* d_ws, size_t ws_size,
                              hipStream_t stream) {
    const float* x     = (const float*)d_in[0];
    const int*   ei    = (const int*)d_in[1];
    const int*   batch = (const int*)d_in[2];
    const int*   src   = ei;
    const int*   dst   = ei + N_EDGES;

    const float* c_w1[3] = { (const float*)d_in[3],  (const float*)d_in[7],  (const float*)d_in[11] };
    const float* c_b1[3] = { (const float*)d_in[4],  (const float*)d_in[8],  (const float*)d_in[12] };
    const float* c_w2[3] = { (const float*)d_in[5],  (const float*)d_in[9],  (const float*)d_in[13] };
    const float* c_b2[3] = { (const float*)d_in[6],  (const float*)d_in[10], (const float*)d_in[14] };
    const float* out_w1 = (const float*)d_in[15];
    const float* out_b1 = (const float*)d_in[16];
    const float* out_w2 = (const float*)d_in[17];
    const float* out_b2 = (const float*)d_in[18];

    // Workspace layout
    size_t nodeBuf = (size_t)N_NODES * HID;          // 12.8M floats = 51.2 MB
    float* bufA   = (float*)d_ws;                    // h (layer input / output)
    float* bufB   = bufA + nodeBuf;                  // agg (= h + sum of neighbors)
    float* bufC   = bufB + nodeBuf;                  // MLP hidden
    float* sums   = bufC + nodeBuf;                  // 512 x 256
    float* counts = sums + (size_t)N_GRAPHS * HID;   // 512

    dim3 gemmGrid((N_NODES + 63) / 64, HID / 64);

    // ---- Layer 0 (C_in = 128) ----
    hipMemcpyAsync(bufB, x, sizeof(float) * (size_t)N_NODES * IN_C,
                   hipMemcpyDeviceToDevice, stream);
    {
        long total = (long)N_EDGES * (IN_C / 4);
        int blocks = (int)((total + 255) / 256);
        scatter_add_kernel<<<blocks, 256, 0, stream>>>(x, src, dst, bufB, N_EDGES, IN_C, 5);
    }
    gemm_bias_relu<<<gemmGrid, 256, 0, stream>>>(bufB, c_w1[0], c_b1[0], bufC,
                                                 N_NODES, IN_C, HID, 1);
    gemm_bias_relu<<<gemmGrid, 256, 0, stream>>>(bufC, c_w2[0], c_b2[0], bufA,
                                                 N_NODES, HID, HID, 1);

    // ---- Layers 1, 2 (C = 256) ----
    for (int li = 1; li < 3; ++li) {
        hipMemcpyAsync(bufB, bufA, sizeof(float) * nodeBuf,
                       hipMemcpyDeviceToDevice, stream);
        long total = (long)N_EDGES * (HID / 4);
        int blocks = (int)((total + 255) / 256);
        scatter_add_kernel<<<blocks, 256, 0, stream>>>(bufA, src, dst, bufB, N_EDGES, HID, 6);
        gemm_bias_relu<<<gemmGrid, 256, 0, stream>>>(bufB, c_w1[li], c_b1[li], bufC,
                                                     N_NODES, HID, HID, 1);
        gemm_bias_relu<<<gemmGrid, 256, 0, stream>>>(bufC, c_w2[li], c_b2[li], bufA,
                                                     N_NODES, HID, HID, 1);
    }

    // ---- Global mean pool ----
    hipMemsetAsync(sums, 0, sizeof(float) * ((size_t)N_GRAPHS * HID + N_GRAPHS), stream);
    {
        long total = (long)N_NODES * (HID / 4);
        int blocks = (int)((total + 255) / 256);
        pool_kernel<<<blocks, 256, 0, stream>>>(bufA, batch, sums, counts);
    }

    // ---- Head MLP ----
    final_mlp_kernel<<<N_GRAPHS, 256, 0, stream>>>(sums, counts, out_w1, out_b1,
                                                   out_w2, out_b2, (float*)d_out);
}

// Round 2
// 1132.288 us; speedup vs baseline: 6.7126x; 6.7126x over previous
//
#include <hip/hip_runtime.h>

#define N_NODES 50000
#define N_EDGES 800000
#define N_GRAPHS 512
#define IN_C 128
#define HID 256
#define OUT_C 16

// ===========================================================================
// CSR build: deg histogram -> 2-level exclusive scan -> bucket edges by dst.
// ~2.5M int atomics total (vs 460M float atomics in the old scatter).
// ===========================================================================
__global__ void deg_kernel(const int* __restrict__ dst, int* __restrict__ deg) {
    int e = blockIdx.x * blockDim.x + threadIdx.x;
    if (e < N_EDGES) atomicAdd(&deg[dst[e]], 1);
}

// Per-block (256-elem) inclusive scan; writes exclusive-within-block + block sum.
__global__ __launch_bounds__(256) void scan_block(const int* __restrict__ deg,
                                                  int* __restrict__ partial,
                                                  int* __restrict__ blockSums) {
    __shared__ int s[256];
    int t = threadIdx.x;
    int i = blockIdx.x * 256 + t;
    int v = (i < N_NODES) ? deg[i] : 0;
    s[t] = v;
    __syncthreads();
    #pragma unroll
    for (int off = 1; off < 256; off <<= 1) {
        int add = (t >= off) ? s[t - off] : 0;
        __syncthreads();
        s[t] += add;
        __syncthreads();
    }
    if (i < N_NODES) partial[i] = s[t] - v;   // exclusive within block
    if (t == 255) blockSums[blockIdx.x] = s[255];
}

// Single-block exclusive scan of the block sums (nb <= 256).
__global__ __launch_bounds__(256) void scan_sums(int* __restrict__ blockSums, int nb) {
    __shared__ int s[256];
    int t = threadIdx.x;
    int v = (t < nb) ? blockSums[t] : 0;
    s[t] = v;
    __syncthreads();
    #pragma unroll
    for (int off = 1; off < 256; off <<= 1) {
        int add = (t >= off) ? s[t - off] : 0;
        __syncthreads();
        s[t] += add;
        __syncthreads();
    }
    if (t < nb) blockSums[t] = s[t] - v;      // exclusive
}

__global__ void add_offsets(const int* __restrict__ partial,
                            const int* __restrict__ blockSums,
                            int* __restrict__ rowptr) {
    int i = blockIdx.x * 256 + threadIdx.x;
    if (i < N_NODES) rowptr[i] = partial[i] + blockSums[blockIdx.x];
    if (i == 0) rowptr[N_NODES] = N_EDGES;
}

// cursor starts as a copy of rowptr; fetch-add gives each edge its slot.
__global__ void bucket_edges(const int* __restrict__ src, const int* __restrict__ dst,
                             int* __restrict__ cursor, int* __restrict__ srcSorted) {
    int e = blockIdx.x * blockDim.x + threadIdx.x;
    if (e >= N_EDGES) return;
    int p = atomicAdd(&cursor[dst[e]], 1);
    srcSorted[p] = src[e];
}

// ===========================================================================
// Aggregation as gather: out[n] = h[n] + sum_{s in N_in(n)} h[s].
// One wave (64 lanes) per node; lane owns C/64 contiguous channels.
// No atomics; h is LLC-resident (51 MB < 256 MB).
// ===========================================================================
template <int C>
__global__ __launch_bounds__(256) void gin_aggregate(const float* __restrict__ h,
                                                     const int* __restrict__ rowptr,
                                                     const int* __restrict__ srcIdx,
                                                     float* __restrict__ out) {
    constexpr int VEC = C / 64;   // 4 (C=256) or 2 (C=128)
    int wave = threadIdx.x >> 6;
    int lane = threadIdx.x & 63;
    int node = blockIdx.x * 4 + wave;
    if (node >= N_NODES) return;
    int off = lane * VEC;

    float acc[VEC];
    const float* hp = h + (long)node * C + off;
    if constexpr (VEC == 4) {
        float4 s = *(const float4*)hp;
        acc[0] = s.x; acc[1] = s.y; acc[2] = s.z; acc[3] = s.w;
    } else {
        float2 s = *(const float2*)hp;
        acc[0] = s.x; acc[1] = s.y;
    }

    int beg = rowptr[node];
    int end = rowptr[node + 1];
    for (int k = beg; k < end; ++k) {
        int s = srcIdx[k];
        const float* rp = h + (long)s * C + off;
        if constexpr (VEC == 4) {
            float4 r = *(const float4*)rp;
            acc[0] += r.x; acc[1] += r.y; acc[2] += r.z; acc[3] += r.w;
        } else {
            float2 r = *(const float2*)rp;
            acc[0] += r.x; acc[1] += r.y;
        }
    }

    float* op = out + (long)node * C + off;
    if constexpr (VEC == 4) {
        float4 o; o.x = acc[0]; o.y = acc[1]; o.z = acc[2]; o.w = acc[3];
        *(float4*)op = o;
    } else {
        float2 o; o.x = acc[0]; o.y = acc[1];
        *(float2*)op = o;
    }
}

// ---------------------------------------------------------------------------
// Tiled fp32 GEMM with fused bias + optional ReLU. (unchanged from R1)
// ---------------------------------------------------------------------------
__global__ __launch_bounds__(256) void gemm_bias_relu(
    const float* __restrict__ A, const float* __restrict__ W,
    const float* __restrict__ bias, float* __restrict__ C,
    int M, int K, int N, int doRelu) {
    const int BM = 64, BN = 64, BK = 32;
    __shared__ float As[BK][BM];
    __shared__ float Bs[BK][BN + 4];

    int t = threadIdx.x;
    int tx = t & 15;
    int ty = t >> 4;
    int block_row = blockIdx.x * BM;
    int block_col = blockIdx.y * BN;

    float acc[4][4] = {};

    for (int k0 = 0; k0 < K; k0 += BK) {
        #pragma unroll
        for (int l = 0; l < 2; ++l) {
            int idx = t + l * 256;
            int m = idx >> 3;
            int kk = (idx & 7) << 2;
            int grow = block_row + m;
            float4 v = make_float4(0.f, 0.f, 0.f, 0.f);
            if (grow < M) v = *(const float4*)(A + (long)grow * K + k0 + kk);
            As[kk + 0][m] = v.x;
            As[kk + 1][m] = v.y;
            As[kk + 2][m] = v.z;
            As[kk + 3][m] = v.w;
        }
        #pragma unroll
        for (int l = 0; l < 2; ++l) {
            int idx = t + l * 256;
            int kk = idx >> 4;
            int nn = (idx & 15) << 2;
            float4 v = *(const float4*)(W + (long)(k0 + kk) * N + block_col + nn);
            *(float4*)&Bs[kk][nn] = v;
        }
        __syncthreads();

        #pragma unroll
        for (int kk = 0; kk < BK; ++kk) {
            float a[4], b[4];
            #pragma unroll
            for (int i = 0; i < 4; ++i) a[i] = As[kk][ty * 4 + i];
            #pragma unroll
            for (int j = 0; j < 4; ++j) b[j] = Bs[kk][tx * 4 + j];
            #pragma unroll
            for (int i = 0; i < 4; ++i)
                #pragma unroll
                for (int j = 0; j < 4; ++j)
                    acc[i][j] += a[i] * b[j];
        }
        __syncthreads();
    }

    int gcol = block_col + tx * 4;
    float4 bv = *(const float4*)(bias + gcol);
    #pragma unroll
    for (int i = 0; i < 4; ++i) {
        int grow = block_row + ty * 4 + i;
        if (grow >= M) continue;
        float4 o;
        o.x = acc[i][0] + bv.x;
        o.y = acc[i][1] + bv.y;
        o.z = acc[i][2] + bv.z;
        o.w = acc[i][3] + bv.w;
        if (doRelu) {
            o.x = fmaxf(o.x, 0.f); o.y = fmaxf(o.y, 0.f);
            o.z = fmaxf(o.z, 0.f); o.w = fmaxf(o.w, 0.f);
        }
        *(float4*)(C + (long)grow * N + gcol) = o;
    }
}

// ---------------------------------------------------------------------------
// Mean-pool: block = 64-node tile, 256 threads (4 node-lanes x 64 chan-chunks).
// batch is sorted -> run-length accumulate, flush atomics only on graph change.
// ---------------------------------------------------------------------------
__global__ __launch_bounds__(256) void pool_kernel(const float* __restrict__ h,
                                                   const int* __restrict__ batch,
                                                   float* __restrict__ sums) {
    int base = blockIdx.x * 64;
    int t = threadIdx.x;
    int c4 = (t & 63) << 2;     // channel chunk
    int r0 = t >> 6;            // node sub-lane 0..3
    float4 acc = make_float4(0.f, 0.f, 0.f, 0.f);
    int cur = -1;
    for (int i = r0; i < 64; i += 4) {
        int n = base + i;
        if (n >= N_NODES) break;
        int g = batch[n];
        if (g != cur) {
            if (cur >= 0) {
                float* p = sums + (long)cur * HID + c4;
                atomicAdd(p + 0, acc.x); atomicAdd(p + 1, acc.y);
                atomicAdd(p + 2, acc.z); atomicAdd(p + 3, acc.w);
            }
            cur = g;
            acc = make_float4(0.f, 0.f, 0.f, 0.f);
        }
        float4 v = *(const float4*)(h + (long)n * HID + c4);
        acc.x += v.x; acc.y += v.y; acc.z += v.z; acc.w += v.w;
    }
    if (cur >= 0) {
        float* p = sums + (long)cur * HID + c4;
        atomicAdd(p + 0, acc.x); atomicAdd(p + 1, acc.y);
        atomicAdd(p + 2, acc.z); atomicAdd(p + 3, acc.w);
    }
}

__global__ void count_kernel(const int* __restrict__ batch, float* __restrict__ counts) {
    int n = blockIdx.x * blockDim.x + threadIdx.x;
    if (n < N_NODES) atomicAdd(&counts[batch[n]], 1.0f);
}

// ---------------------------------------------------------------------------
// Head MLP: one block per graph.
// ---------------------------------------------------------------------------
__global__ __launch_bounds__(256) void final_mlp_kernel(
    const float* __restrict__ sums, const float* __restrict__ counts,
    const float* __restrict__ w1, const float* __restrict__ b1,
    const float* __restrict__ w2, const float* __restrict__ b2,
    float* __restrict__ out) {
    __shared__ float row[HID];
    __shared__ float hid[HID];
    int g = blockIdx.x;
    int t = threadIdx.x;
    float cnt = fmaxf(counts[g], 1.0f);
    row[t] = sums[(long)g * HID + t] / cnt;
    __syncthreads();
    float acc = b1[t];
    for (int k = 0; k < HID; ++k) acc += row[k] * w1[k * HID + t];
    hid[t] = fmaxf(acc, 0.f);
    __syncthreads();
    if (t < OUT_C) {
        float o = b2[t];
        for (int k = 0; k < HID; ++k) o += hid[k] * w2[k * OUT_C + t];
        out[(long)g * OUT_C + t] = o;
    }
}

// ---------------------------------------------------------------------------
extern "C" void kernel_launch(void* const* d_in, const int* in_sizes, int n_in,
                              void* d_out, int out_size, void* d_ws, size_t ws_size,
                              hipStream_t stream) {
    const float* x     = (const float*)d_in[0];
    const int*   ei    = (const int*)d_in[1];
    const int*   batch = (const int*)d_in[2];
    const int*   src   = ei;
    const int*   dst   = ei + N_EDGES;

    const float* c_w1[3] = { (const float*)d_in[3],  (const float*)d_in[7],  (const float*)d_in[11] };
    const float* c_b1[3] = { (const float*)d_in[4],  (const float*)d_in[8],  (const float*)d_in[12] };
    const float* c_w2[3] = { (const float*)d_in[5],  (const float*)d_in[9],  (const float*)d_in[13] };
    const float* c_b2[3] = { (const float*)d_in[6],  (const float*)d_in[10], (const float*)d_in[14] };
    const float* out_w1 = (const float*)d_in[15];
    const float* out_b1 = (const float*)d_in[16];
    const float* out_w2 = (const float*)d_in[17];
    const float* out_b2 = (const float*)d_in[18];

    // ---- Workspace layout ----
    size_t nodeBuf = (size_t)N_NODES * HID;          // 12.8M floats
    float* bufA   = (float*)d_ws;                    // h (layer in/out)
    float* bufB   = bufA + nodeBuf;                  // agg
    float* bufC   = bufB + nodeBuf;                  // MLP hidden
    float* sums   = bufC + nodeBuf;                  // 512 x 256
    float* counts = sums + (size_t)N_GRAPHS * HID;   // 512
    int* deg       = (int*)(counts + N_GRAPHS);      // 50000
    int* rowptr    = deg + N_NODES;                  // 50001
    int* blockSums = rowptr + N_NODES + 1;           // 256
    int* cursor    = blockSums + 256;                // 50000
    int* srcSorted = cursor + N_NODES;               // 800000

    const int nb = (N_NODES + 255) / 256;            // 196 scan blocks

    // ---- Build CSR by dst (once; edge list is static across layers) ----
    hipMemsetAsync(deg, 0, sizeof(int) * N_NODES, stream);
    deg_kernel<<<(N_EDGES + 255) / 256, 256, 0, stream>>>(dst, deg);
    scan_block<<<nb, 256, 0, stream>>>(deg, rowptr, blockSums);
    scan_sums<<<1, 256, 0, stream>>>(blockSums, nb);
    add_offsets<<<nb, 256, 0, stream>>>(rowptr, blockSums, rowptr);
    hipMemcpyAsync(cursor, rowptr, sizeof(int) * N_NODES, hipMemcpyDeviceToDevice, stream);
    bucket_edges<<<(N_EDGES + 255) / 256, 256, 0, stream>>>(src, dst, cursor, srcSorted);

    dim3 gemmGrid((N_NODES + 63) / 64, HID / 64);
    const int aggGrid = (N_NODES + 3) / 4;

    // ---- Layer 0 (C_in = 128) ----
    gin_aggregate<IN_C><<<aggGrid, 256, 0, stream>>>(x, rowptr, srcSorted, bufB);
    gemm_bias_relu<<<gemmGrid, 256, 0, stream>>>(bufB, c_w1[0], c_b1[0], bufC,
                                                 N_NODES, IN_C, HID, 1);
    gemm_bias_relu<<<gemmGrid, 256, 0, stream>>>(bufC, c_w2[0], c_b2[0], bufA,
                                                 N_NODES, HID, HID, 1);

    // ---- Layers 1, 2 (C = 256) ----
    for (int li = 1; li < 3; ++li) {
        gin_aggregate<HID><<<aggGrid, 256, 0, stream>>>(bufA, rowptr, srcSorted, bufB);
        gemm_bias_relu<<<gemmGrid, 256, 0, stream>>>(bufB, c_w1[li], c_b1[li], bufC,
                                                     N_NODES, HID, HID, 1);
        gemm_bias_relu<<<gemmGrid, 256, 0, stream>>>(bufC, c_w2[li], c_b2[li], bufA,
                                                     N_NODES, HID, HID, 1);
    }

    // ---- Global mean pool ----
    hipMemsetAsync(sums, 0, sizeof(float) * ((size_t)N_GRAPHS * HID + N_GRAPHS), stream);
    pool_kernel<<<(N_NODES + 63) / 64, 256, 0, stream>>>(bufA, batch, sums);
    count_kernel<<<(N_NODES + 255) / 256, 256, 0, stream>>>(batch, counts);

    // ---- Head MLP ----
    final_mlp_kernel<<<N_GRAPHS, 256, 0, stream>>>(sums, counts, out_w1, out_b1,
                                                   out_w2, out_b2, (float*)d_out);
}

// Round 3
// 673.023 us; speedup vs baseline: 11.2932x; 1.6824x over previous
//
#include <hip/hip_runtime.h>

#define N_NODES 50000
#define N_EDGES 800000
#define N_GRAPHS 512
#define IN_C 128
#define HID 256
#define OUT_C 16

typedef __attribute__((ext_vector_type(8))) short short8;
typedef __attribute__((ext_vector_type(4))) float f32x4;

__device__ __forceinline__ float bf2f(unsigned short u) {
    return __uint_as_float(((unsigned int)u) << 16);
}
__device__ __forceinline__ unsigned short f2bf(float f) {
    unsigned int u = __float_as_uint(f);
    u += 0x7fff + ((u >> 16) & 1);   // RNE
    return (unsigned short)(u >> 16);
}

// ===========================================================================
// Prep: fp32 -> bf16 casts.
// ===========================================================================
__global__ void cast_x_kernel(const float* __restrict__ in, ushort* __restrict__ out, int n4) {
    int i = blockIdx.x * blockDim.x + threadIdx.x;
    if (i >= n4) return;
    float4 v = *(const float4*)(in + (long)i * 4);
    ushort4 o;
    o.x = f2bf(v.x); o.y = f2bf(v.y); o.z = f2bf(v.z); o.w = f2bf(v.w);
    *(ushort4*)(out + (long)i * 4) = o;
}

// w: K x N fp32 (row-major) -> wt: N x K bf16 (row-major, i.e. transposed)
__global__ void transpose_cast_kernel(const float* __restrict__ w, ushort* __restrict__ wt,
                                      int K, int N) {
    int i = blockIdx.x * blockDim.x + threadIdx.x;
    if (i >= N * K) return;
    int n = i / K;
    int k = i - n * K;
    wt[i] = f2bf(w[(long)k * N + n]);
}

// ===========================================================================
// CSR build: deg histogram -> 2-level exclusive scan -> bucket edges by dst.
// ===========================================================================
__global__ void deg_kernel(const int* __restrict__ dst, int* __restrict__ deg) {
    int e = blockIdx.x * blockDim.x + threadIdx.x;
    if (e < N_EDGES) atomicAdd(&deg[dst[e]], 1);
}

__global__ __launch_bounds__(256) void scan_block(const int* __restrict__ deg,
                                                  int* __restrict__ partial,
                                                  int* __restrict__ blockSums) {
    __shared__ int s[256];
    int t = threadIdx.x;
    int i = blockIdx.x * 256 + t;
    int v = (i < N_NODES) ? deg[i] : 0;
    s[t] = v;
    __syncthreads();
    #pragma unroll
    for (int off = 1; off < 256; off <<= 1) {
        int add = (t >= off) ? s[t - off] : 0;
        __syncthreads();
        s[t] += add;
        __syncthreads();
    }
    if (i < N_NODES) partial[i] = s[t] - v;
    if (t == 255) blockSums[blockIdx.x] = s[255];
}

__global__ __launch_bounds__(256) void scan_sums(int* __restrict__ blockSums, int nb) {
    __shared__ int s[256];
    int t = threadIdx.x;
    int v = (t < nb) ? blockSums[t] : 0;
    s[t] = v;
    __syncthreads();
    #pragma unroll
    for (int off = 1; off < 256; off <<= 1) {
        int add = (t >= off) ? s[t - off] : 0;
        __syncthreads();
        s[t] += add;
        __syncthreads();
    }
    if (t < nb) blockSums[t] = s[t] - v;
}

__global__ void add_offsets(const int* __restrict__ partial,
                            const int* __restrict__ blockSums,
                            int* __restrict__ rowptr) {
    int i = blockIdx.x * 256 + threadIdx.x;
    if (i < N_NODES) rowptr[i] = partial[i] + blockSums[blockIdx.x];
    if (i == 0) rowptr[N_NODES] = N_EDGES;
}

__global__ void bucket_edges(const int* __restrict__ src, const int* __restrict__ dst,
                             int* __restrict__ cursor, int* __restrict__ srcSorted) {
    int e = blockIdx.x * blockDim.x + threadIdx.x;
    if (e >= N_EDGES) return;
    int p = atomicAdd(&cursor[dst[e]], 1);
    srcSorted[p] = src[e];
}

// ===========================================================================
// Aggregation (bf16 in/out, fp32 accumulate): out[n] = h[n] + sum h[src].
// One wave per node; lane owns C/64 channels.
// ===========================================================================
template <int C>
__global__ __launch_bounds__(256) void gin_aggregate_bf(const ushort* __restrict__ h,
                                                        const int* __restrict__ rowptr,
                                                        const int* __restrict__ srcIdx,
                                                        ushort* __restrict__ out) {
    constexpr int VEC = C / 64;   // 4 (C=256) or 2 (C=128)
    int wave = threadIdx.x >> 6;
    int lane = threadIdx.x & 63;
    int node = blockIdx.x * 4 + wave;
    if (node >= N_NODES) return;
    int off = lane * VEC;

    float acc[VEC];
    {
        const ushort* hp = h + (long)node * C + off;
        if constexpr (VEC == 4) {
            ushort4 s = *(const ushort4*)hp;
            acc[0] = bf2f(s.x); acc[1] = bf2f(s.y); acc[2] = bf2f(s.z); acc[3] = bf2f(s.w);
        } else {
            ushort2 s = *(const ushort2*)hp;
            acc[0] = bf2f(s.x); acc[1] = bf2f(s.y);
        }
    }

    int beg = rowptr[node];
    int end = rowptr[node + 1];
    for (int k = beg; k < end; ++k) {
        int s = srcIdx[k];
        const ushort* rp = h + (long)s * C + off;
        if constexpr (VEC == 4) {
            ushort4 r = *(const ushort4*)rp;
            acc[0] += bf2f(r.x); acc[1] += bf2f(r.y); acc[2] += bf2f(r.z); acc[3] += bf2f(r.w);
        } else {
            ushort2 r = *(const ushort2*)rp;
            acc[0] += bf2f(r.x); acc[1] += bf2f(r.y);
        }
    }

    ushort* op = out + (long)node * C + off;
    if constexpr (VEC == 4) {
        ushort4 o;
        o.x = f2bf(acc[0]); o.y = f2bf(acc[1]); o.z = f2bf(acc[2]); o.w = f2bf(acc[3]);
        *(ushort4*)op = o;
    } else {
        ushort2 o;
        o.x = f2bf(acc[0]); o.y = f2bf(acc[1]);
        *(ushort2*)op = o;
    }
}

// ===========================================================================
// bf16 MFMA GEMM: C[M,N] = A[M,K] @ W[K,N] + bias (+ReLU), bf16 in/out.
// Wt is the transposed weight (N x K). BM=BN=128, BK=32, 256 thr (4 waves),
// each wave does a 64x64 sub-tile via 4x4 grid of 16x16x32 MFMAs.
// LDS layout: 16B chunks, chunk(q, m) = tile[m][q*8 .. q*8+8), idx = q*128+m.
// ===========================================================================
__global__ __launch_bounds__(256) void gemm_bf16(
    const ushort* __restrict__ A,   // M x K bf16
    const ushort* __restrict__ Wt,  // N x K bf16 (transposed weight)
    const float* __restrict__ bias, // N fp32
    ushort* __restrict__ C,         // M x N bf16
    int M, int K, int N, int doRelu) {
    __shared__ short As[128 * 32];
    __shared__ short Bs[128 * 32];

    int t = threadIdx.x;
    int lane = t & 63;
    int wv = t >> 6;
    int R0 = (wv >> 1) * 64;
    int C0 = (wv & 1) * 64;
    int quad = lane >> 4;
    int l15 = lane & 15;
    int block_row = blockIdx.x * 128;
    int block_col = blockIdx.y * 128;

    const f32x4 zero = {0.f, 0.f, 0.f, 0.f};
    f32x4 acc[4][4];
    #pragma unroll
    for (int i = 0; i < 4; ++i)
        #pragma unroll
        for (int j = 0; j < 4; ++j) acc[i][j] = zero;

    // staging coords: thread t loads chunks (qa, ma) and (qa, ma+64)
    int qa = t & 3;
    int ma = t >> 2;

    for (int k0 = 0; k0 < K; k0 += 32) {
        #pragma unroll
        for (int hh = 0; hh < 2; ++hh) {
            int m = ma + hh * 64;
            int row = block_row + m;
            if (row >= M) row = M - 1;                       // clamp (stores guarded)
            short8 v = *(const short8*)(A + (long)row * K + k0 + qa * 8);
            *(short8*)&As[(qa * 128 + m) * 8] = v;
        }
        #pragma unroll
        for (int hh = 0; hh < 2; ++hh) {
            int n = ma + hh * 64;
            short8 v = *(const short8*)(Wt + (long)(block_col + n) * K + k0 + qa * 8);
            *(short8*)&Bs[(qa * 128 + n) * 8] = v;
        }
        __syncthreads();

        short8 a[4], b[4];
        #pragma unroll
        for (int i = 0; i < 4; ++i)
            a[i] = *(const short8*)&As[(quad * 128 + R0 + i * 16 + l15) * 8];
        #pragma unroll
        for (int j = 0; j < 4; ++j)
            b[j] = *(const short8*)&Bs[(quad * 128 + C0 + j * 16 + l15) * 8];

        #pragma unroll
        for (int i = 0; i < 4; ++i)
            #pragma unroll
            for (int j = 0; j < 4; ++j)
                acc[i][j] = __builtin_amdgcn_mfma_f32_16x16x32_bf16(a[i], b[j], acc[i][j], 0, 0, 0);
        __syncthreads();
    }

    // Epilogue: bias + relu + cast. C/D layout: col = l15, row = quad*4 + r.
    float bv[4];
    #pragma unroll
    for (int j = 0; j < 4; ++j) bv[j] = bias[block_col + C0 + j * 16 + l15];

    #pragma unroll
    for (int i = 0; i < 4; ++i) {
        #pragma unroll
        for (int r = 0; r < 4; ++r) {
            int row = block_row + R0 + i * 16 + quad * 4 + r;
            if (row >= M) continue;
            #pragma unroll
            for (int j = 0; j < 4; ++j) {
                float o = acc[i][j][r] + bv[j];
                if (doRelu) o = fmaxf(o, 0.f);
                C[(long)row * N + block_col + C0 + j * 16 + l15] = f2bf(o);
            }
        }
    }
}

// ===========================================================================
// Mean-pool (bf16 h -> fp32 sums): run-length flush, batch is sorted.
// ===========================================================================
__global__ __launch_bounds__(256) void pool_kernel_bf(const ushort* __restrict__ h,
                                                      const int* __restrict__ batch,
                                                      float* __restrict__ sums) {
    int base = blockIdx.x * 64;
    int t = threadIdx.x;
    int c4 = (t & 63) << 2;
    int r0 = t >> 6;
    float a0 = 0.f, a1 = 0.f, a2 = 0.f, a3 = 0.f;
    int cur = -1;
    for (int i = r0; i < 64; i += 4) {
        int n = base + i;
        if (n >= N_NODES) break;
        int g = batch[n];
        if (g != cur) {
            if (cur >= 0) {
                float* p = sums + (long)cur * HID + c4;
                atomicAdd(p + 0, a0); atomicAdd(p + 1, a1);
                atomicAdd(p + 2, a2); atomicAdd(p + 3, a3);
            }
            cur = g;
            a0 = a1 = a2 = a3 = 0.f;
        }
        ushort4 v = *(const ushort4*)(h + (long)n * HID + c4);
        a0 += bf2f(v.x); a1 += bf2f(v.y); a2 += bf2f(v.z); a3 += bf2f(v.w);
    }
    if (cur >= 0) {
        float* p = sums + (long)cur * HID + c4;
        atomicAdd(p + 0, a0); atomicAdd(p + 1, a1);
        atomicAdd(p + 2, a2); atomicAdd(p + 3, a3);
    }
}

__global__ void count_kernel(const int* __restrict__ batch, float* __restrict__ counts) {
    int n = blockIdx.x * blockDim.x + threadIdx.x;
    if (n < N_NODES) atomicAdd(&counts[batch[n]], 1.0f);
}

// ===========================================================================
// Head MLP (fp32): one block per graph.
// ===========================================================================
__global__ __launch_bounds__(256) void final_mlp_kernel(
    const float* __restrict__ sums, const float* __restrict__ counts,
    const float* __restrict__ w1, const float* __restrict__ b1,
    const float* __restrict__ w2, const float* __restrict__ b2,
    float* __restrict__ out) {
    __shared__ float row[HID];
    __shared__ float hid[HID];
    int g = blockIdx.x;
    int t = threadIdx.x;
    float cnt = fmaxf(counts[g], 1.0f);
    row[t] = sums[(long)g * HID + t] / cnt;
    __syncthreads();
    float acc = b1[t];
    for (int k = 0; k < HID; ++k) acc += row[k] * w1[k * HID + t];
    hid[t] = fmaxf(acc, 0.f);
    __syncthreads();
    if (t < OUT_C) {
        float o = b2[t];
        for (int k = 0; k < HID; ++k) o += hid[k] * w2[k * OUT_C + t];
        out[(long)g * OUT_C + t] = o;
    }
}

// ---------------------------------------------------------------------------
extern "C" void kernel_launch(void* const* d_in, const int* in_sizes, int n_in,
                              void* d_out, int out_size, void* d_ws, size_t ws_size,
                              hipStream_t stream) {
    const float* x     = (const float*)d_in[0];
    const int*   ei    = (const int*)d_in[1];
    const int*   batch = (const int*)d_in[2];
    const int*   src   = ei;
    const int*   dst   = ei + N_EDGES;

    const float* c_w1[3] = { (const float*)d_in[3],  (const float*)d_in[7],  (const float*)d_in[11] };
    const float* c_b1[3] = { (const float*)d_in[4],  (const float*)d_in[8],  (const float*)d_in[12] };
    const float* c_w2[3] = { (const float*)d_in[5],  (const float*)d_in[9],  (const float*)d_in[13] };
    const float* c_b2[3] = { (const float*)d_in[6],  (const float*)d_in[10], (const float*)d_in[14] };
    const float* out_w1 = (const float*)d_in[15];
    const float* out_b1 = (const float*)d_in[16];
    const float* out_w2 = (const float*)d_in[17];
    const float* out_b2 = (const float*)d_in[18];

    // ---- Workspace layout (16B aligned regions) ----
    char* p = (char*)d_ws;
    auto alloc = [&](size_t bytes) {
        char* r = p;
        p += (bytes + 15) & ~(size_t)15;
        return r;
    };
    ushort* xbf  = (ushort*)alloc((size_t)N_NODES * IN_C * 2);
    ushort* bufA = (ushort*)alloc((size_t)N_NODES * HID * 2);
    ushort* bufB = (ushort*)alloc((size_t)N_NODES * HID * 2);
    ushort* bufC = (ushort*)alloc((size_t)N_NODES * HID * 2);
    ushort* wt[6];
    wt[0] = (ushort*)alloc((size_t)IN_C * HID * 2);        // c0_w1^T: 256 x 128
    for (int i = 1; i < 6; ++i) wt[i] = (ushort*)alloc((size_t)HID * HID * 2);
    float* sums   = (float*)alloc((size_t)N_GRAPHS * HID * 4);
    float* counts = (float*)alloc((size_t)N_GRAPHS * 4);
    int* deg       = (int*)alloc((size_t)N_NODES * 4);
    int* rowptr    = (int*)alloc((size_t)(N_NODES + 1) * 4);
    int* blockSums = (int*)alloc(256 * 4);
    int* cursor    = (int*)alloc((size_t)N_NODES * 4);
    int* srcSorted = (int*)alloc((size_t)N_EDGES * 4);

    const int nb = (N_NODES + 255) / 256;

    // ---- Prep: casts (x -> bf16; weights -> transposed bf16) ----
    {
        int n4 = N_NODES * IN_C / 4;
        cast_x_kernel<<<(n4 + 255) / 256, 256, 0, stream>>>(x, xbf, n4);
    }
    transpose_cast_kernel<<<(IN_C * HID + 255) / 256, 256, 0, stream>>>(c_w1[0], wt[0], IN_C, HID);
    transpose_cast_kernel<<<(HID * HID + 255) / 256, 256, 0, stream>>>(c_w2[0], wt[1], HID, HID);
    transpose_cast_kernel<<<(HID * HID + 255) / 256, 256, 0, stream>>>(c_w1[1], wt[2], HID, HID);
    transpose_cast_kernel<<<(HID * HID + 255) / 256, 256, 0, stream>>>(c_w2[1], wt[3], HID, HID);
    transpose_cast_kernel<<<(HID * HID + 255) / 256, 256, 0, stream>>>(c_w1[2], wt[4], HID, HID);
    transpose_cast_kernel<<<(HID * HID + 255) / 256, 256, 0, stream>>>(c_w2[2], wt[5], HID, HID);

    // ---- Build CSR by dst ----
    hipMemsetAsync(deg, 0, sizeof(int) * N_NODES, stream);
    deg_kernel<<<(N_EDGES + 255) / 256, 256, 0, stream>>>(dst, deg);
    scan_block<<<nb, 256, 0, stream>>>(deg, rowptr, blockSums);
    scan_sums<<<1, 256, 0, stream>>>(blockSums, nb);
    add_offsets<<<nb, 256, 0, stream>>>(rowptr, blockSums, rowptr);
    hipMemcpyAsync(cursor, rowptr, sizeof(int) * N_NODES, hipMemcpyDeviceToDevice, stream);
    bucket_edges<<<(N_EDGES + 255) / 256, 256, 0, stream>>>(src, dst, cursor, srcSorted);

    dim3 gemmGrid((N_NODES + 127) / 128, HID / 128);   // 391 x 2
    const int aggGrid = (N_NODES + 3) / 4;

    // ---- Layer 0 (C_in = 128) ----
    gin_aggregate_bf<IN_C><<<aggGrid, 256, 0, stream>>>(xbf, rowptr, srcSorted, bufB);
    gemm_bf16<<<gemmGrid, 256, 0, stream>>>(bufB, wt[0], c_b1[0], bufC, N_NODES, IN_C, HID, 1);
    gemm_bf16<<<gemmGrid, 256, 0, stream>>>(bufC, wt[1], c_b2[0], bufA, N_NODES, HID, HID, 1);

    // ---- Layers 1, 2 (C = 256) ----
    for (int li = 1; li < 3; ++li) {
        gin_aggregate_bf<HID><<<aggGrid, 256, 0, stream>>>(bufA, rowptr, srcSorted, bufB);
        gemm_bf16<<<gemmGrid, 256, 0, stream>>>(bufB, wt[2 * li], c_b1[li], bufC, N_NODES, HID, HID, 1);
        gemm_bf16<<<gemmGrid, 256, 0, stream>>>(bufC, wt[2 * li + 1], c_b2[li], bufA, N_NODES, HID, HID, 1);
    }

    // ---- Global mean pool ----
    hipMemsetAsync(sums, 0, sizeof(float) * (size_t)N_GRAPHS * HID, stream);
    hipMemsetAsync(counts, 0, sizeof(float) * N_GRAPHS, stream);
    pool_kernel_bf<<<(N_NODES + 63) / 64, 256, 0, stream>>>(bufA, batch, sums);
    count_kernel<<<(N_NODES + 255) / 256, 256, 0, stream>>>(batch, counts);

    // ---- Head MLP (fp32) ----
    final_mlp_kernel<<<N_GRAPHS, 256, 0, stream>>>(sums, counts, out_w1, out_b1,
                                                   out_w2, out_b2, (float*)d_out);
}